// Round 5
// baseline (3757.435 us; speedup 1.0000x reference)
//
#include <hip/hip_runtime.h>
#include <cstdint>

#define NTAP 27
#define CH 32
static constexpr int N_LOW = 16384;
static constexpr int M_ALL = 131072;
static constexpr int NCHMAX = 2048;   // hard bound: M_ALL/64 chunks

// ---------------- init / gt_mask normalization ----------------

__global__ void k_init(int* cnt) {
    int t = threadIdx.x;
    if (t < 64) cnt[t] = 0;
    if (t == 0) cnt[8] = N_LOW;     // low-map row count
}

__global__ __launch_bounds__(256) void k_gt_detect(const unsigned char* __restrict__ p, int* flags) {
    int i = blockIdx.x * 256 + threadIdx.x;
    bool a = false, b = false;
    if (i < M_ALL) {
        unsigned char v = p[i];
        a = ((i & 3) != 0) && (v != 0);
        b = (v > 1);
    }
    unsigned long long ba = __ballot(a);
    unsigned long long bb = __ballot(b);
    if ((threadIdx.x & 63) == 0) {
        if (ba) atomicOr(&flags[32], 1);
        if (bb) atomicOr(&flags[33], 1);
    }
}

__global__ __launch_bounds__(256) void k_gt_norm(const unsigned char* __restrict__ p,
                                                 unsigned char* __restrict__ gt8,
                                                 const int* __restrict__ flags) {
    int i = blockIdx.x * 256 + threadIdx.x;
    if (i >= M_ALL) return;
    bool u8 = (flags[32] != 0) && (flags[33] == 0);
    unsigned char v;
    if (u8) v = (p[i] != 0) ? 1 : 0;
    else    v = (((const int*)p)[i] != 0) ? 1 : 0;
    gt8[i] = v;
}

__global__ __launch_bounds__(256) void k_iota(int* list) {
    int i = blockIdx.x * 256 + threadIdx.x;
    if (i < N_LOW) list[i] = i;
}

// ---------------- low-grid first conv (Cin=1) ----------------

__global__ __launch_bounds__(256) void k_conv_low0(const float* __restrict__ x,
                                                   const int* __restrict__ nbr,
                                                   const float* __restrict__ w0,
                                                   const float* __restrict__ b0,
                                                   float* __restrict__ out) {
    int g = blockIdx.x * 256 + threadIdx.x;
    int n = g >> 5, co = g & 31;
    float acc = b0[co];
    const int* nr = nbr + n * NTAP;
    for (int k = 0; k < NTAP; ++k) {
        int j = nr[k];
        if (j >= 0) acc += x[j] * w0[k * CH + co];
    }
    out[g] = fmaxf(acc, 0.f);
}

// ---------------- ordered compaction (count / scan / emit) ----------------

template<int FIRST>
__global__ __launch_bounds__(256) void k_vcount(unsigned char* __restrict__ valid,
                                                const unsigned char* __restrict__ gt8,
                                                const float* __restrict__ HS,
                                                const float* __restrict__ feats,
                                                float* __restrict__ F,
                                                int* __restrict__ bcnt, int so) {
    int m = blockIdx.x * 256 + threadIdx.x;
    int v;
    if (FIRST) {
        v = ((m & 7) == 0);
    } else {
        int ov = valid[m] & gt8[m];
        int sl = ((m & 7) == so);
        v = ov | sl;
        if (v) {
            const float4* src = (const float4*)((ov ? HS : feats) + (long)m * CH);
            float4* dst = (float4*)(F + (long)m * CH);
            #pragma unroll
            for (int i = 0; i < 8; ++i) dst[i] = src[i];
        }
    }
    valid[m] = (unsigned char)v;
    __shared__ int red[4];
    unsigned long long b = __ballot(v != 0);
    if ((threadIdx.x & 63) == 0) red[threadIdx.x >> 6] = __popcll(b);
    __syncthreads();
    if (threadIdx.x == 0) bcnt[blockIdx.x] = red[0] + red[1] + red[2] + red[3];
}

__global__ void k_scan512(const int* __restrict__ bcnt, int* __restrict__ boff,
                          int* __restrict__ cnt_out) {
    __shared__ int s[512];
    int t = threadIdx.x;
    int mine = bcnt[t];
    s[t] = mine;
    __syncthreads();
    for (int d = 1; d < 512; d <<= 1) {
        int v = (t >= d) ? s[t - d] : 0;
        __syncthreads();
        s[t] += v;
        __syncthreads();
    }
    boff[t] = s[t] - mine;
    if (t == 511) cnt_out[0] = s[511];
}

__global__ __launch_bounds__(256) void k_emit(const unsigned char* __restrict__ valid,
                                              const int* __restrict__ boff,
                                              int* __restrict__ list) {
    int m = blockIdx.x * 256 + threadIdx.x;
    int v = valid[m];
    __shared__ int wof[4];
    unsigned long long b = __ballot(v != 0);
    int lane = threadIdx.x & 63, w = threadIdx.x >> 6;
    int rank = __popcll(b & ((1ull << lane) - 1ull));
    if (lane == 0) wof[w] = __popcll(b);
    __syncthreads();
    int pre = 0;
    for (int i = 0; i < w; ++i) pre += wof[i];
    if (v) list[boff[blockIdx.x] + pre + rank] = m;
}

// ------- pair-list build per (chunk, tap, 16-row quarter): ballot, no atomics -------
// pent[(c*27+k)*64 + q*16 + rank] = (lrow16<<24) | j ; pcnt4[(c*27+k)*4+q] = popcount.

template<int VAL>
__global__ __launch_bounds__(256) void k_pairs3(const int* __restrict__ nbr,
                                                const int* __restrict__ list,
                                                const int* __restrict__ d_count,
                                                const unsigned char* __restrict__ valid,
                                                int* __restrict__ pcnt4,
                                                unsigned int* __restrict__ pent) {
    const int count = d_count[0];
    const int nch = (count + 63) >> 6;
    const int c = blockIdx.x;
    if (c >= nch) return;
    const int t = threadIdx.x, wave = t >> 6, lane = t & 63;
    const int qq = lane >> 4, l16 = lane & 15;
    const int gi = (c << 6) + lane;
    const int m = (gi < count) ? list[gi] : -1;
    const int* nr = nbr + (long)m * NTAP;
    for (int k = wave; k < NTAP; k += 4) {
        int j = -1;
        if (m >= 0) {
            j = nr[k];
            if (VAL && j >= 0 && !valid[j]) j = -1;
        }
        unsigned long long mask = __ballot(j >= 0);
        unsigned qmask = (unsigned)((mask >> (qq * 16)) & 0xFFFFull);
        int rank = __popc(qmask & ((1u << l16) - 1u));
        if (j >= 0)
            pent[(((long)(c * NTAP + k)) << 6) | (qq * 16 + rank)] =
                ((unsigned)l16 << 24) | (unsigned)j;
        if (l16 == 0) pcnt4[(c * NTAP + k) * 4 + qq] = __popc(qmask);
    }
}

// -------- quarter-partitioned conv: wave q owns rows [q*16,q*16+16) of its chunk ------
// No __syncthreads anywhere. One batch per tap (L<=16). Deep cross-tap pipeline:
// ent prefetched 2 taps ahead, W + f-gathers 1 tap ahead (hidden under FMA).

#define INV 0xFFFFFFFFu

template<int RELU, int ADD>
__global__ __launch_bounds__(256) void k_convq(
    const float* __restrict__ f,
    float* __restrict__ out,
    const float* __restrict__ addsrc,
    const float* __restrict__ W,        // [27][32][32]
    const float* __restrict__ bias,     // [32]
    const int* __restrict__ list,
    const int* __restrict__ d_count,
    const int* __restrict__ pcnt4,
    const unsigned int* __restrict__ pent)
{
    __shared__ float accS[4][16 * 36];   // 9216 B: wave-private 16-row acc planes
    __shared__ float wbS[4][1024];       // 16384 B: wave-private W[k]
    __shared__ float fbS[4][16 * 36];    // 9216 B: wave-private staged rows
    const int count = d_count[0];
    const int nch = (count + 63) >> 6;
    const int c = blockIdx.x;
    if (c >= nch) return;
    const int t = threadIdx.x;
    const int wave = t >> 6, lane = t & 63;
    const int slot = lane >> 3, coq = lane & 7;
    float* accw = accS[wave];
    float* wbw = wbS[wave];
    float* fbw = fbS[wave];
    const float4 z4 = make_float4(0.f, 0.f, 0.f, 0.f);
    #pragma unroll
    for (int i = 0; i < 3; ++i) {
        int idx = i * 64 + lane;
        if (idx < 144) ((float4*)accw)[idx] = z4;
    }
    // per-tap quarter counts: lane k<27 holds L_k
    int Lk = 0;
    if (lane < NTAP) Lk = pcnt4[(c * NTAP + lane) * 4 + wave];
    const long pbase = (((long)c * NTAP) << 6) + wave * 16;

    // ---- pipeline prologue: tap 0 fully, ent for tap 1 ----
    int L_cur = __shfl(Lk, 0);
    unsigned e0c = INV, e1c = INV;
    if (slot < L_cur)     e0c = pent[pbase + slot];
    if (slot + 8 < L_cur) e1c = pent[pbase + 8 + slot];
    float4 w0c = z4, w1c = z4, w2c = z4, w3c = z4;
    if (L_cur > 0) {
        const float4* Wg = (const float4*)W;
        w0c = Wg[lane]; w1c = Wg[lane + 64]; w2c = Wg[lane + 128]; w3c = Wg[lane + 192];
    }
    float4 g0c = z4, g1c = z4;
    if (e0c != INV) g0c = ((const float4*)(f + (long)(e0c & 0xFFFFFFu) * CH))[coq];
    if (e1c != INV) g1c = ((const float4*)(f + (long)(e1c & 0xFFFFFFu) * CH))[coq];
    int L_nxt = __shfl(Lk, 1);
    unsigned e0n = INV, e1n = INV;
    if (slot < L_nxt)     e0n = pent[pbase + 64 + slot];
    if (slot + 8 < L_nxt) e1n = pent[pbase + 64 + 8 + slot];

    #pragma unroll 1
    for (int k = 0; k < NTAP; ++k) {
        const int L = L_cur;
        const unsigned e0u = e0c, e1u = e1c;
        // stage current tap to LDS
        if (L > 0) {
            *((float4*)(wbw + lane * 4)) = w0c;
            *((float4*)(wbw + (lane + 64) * 4)) = w1c;
            *((float4*)(wbw + (lane + 128) * 4)) = w2c;
            *((float4*)(wbw + (lane + 192) * 4)) = w3c;
            *((float4*)(fbw + slot * 72 + coq * 4)) = g0c;
            if (L > 8) *((float4*)(fbw + slot * 72 + 36 + coq * 4)) = g1c;
        }
        // prefetch W(k+1)
        float4 nw0 = z4, nw1 = z4, nw2 = z4, nw3 = z4;
        const int Ln1 = L_nxt;
        if (k + 1 < NTAP && Ln1 > 0) {
            const float4* Wg = (const float4*)(W + (long)(k + 1) * 1024);
            nw0 = Wg[lane]; nw1 = Wg[lane + 64]; nw2 = Wg[lane + 128]; nw3 = Wg[lane + 192];
        }
        // prefetch gathers for tap k+1 (ent arrived during previous FMA)
        float4 ng0 = z4, ng1 = z4;
        if (e0n != INV) ng0 = ((const float4*)(f + (long)(e0n & 0xFFFFFFu) * CH))[coq];
        if (e1n != INV) ng1 = ((const float4*)(f + (long)(e1n & 0xFFFFFFu) * CH))[coq];
        // prefetch ent for tap k+2
        unsigned e0f = INV, e1f = INV;
        int Ln2 = 0;
        if (k + 2 < NTAP) {
            Ln2 = __shfl(Lk, k + 2);
            const long pb2 = pbase + ((long)(k + 2) << 6);
            if (slot < Ln2)     e0f = pent[pb2 + slot];
            if (slot + 8 < Ln2) e1f = pent[pb2 + 8 + slot];
        }
        // compute current tap
        if (L > 0) {
            asm volatile("s_waitcnt lgkmcnt(0)" ::: "memory");
            __builtin_amdgcn_sched_barrier(0);
            if (L > 8) {
                float r00 = 0.f, r01 = 0.f, r02 = 0.f, r03 = 0.f;
                float r10 = 0.f, r11 = 0.f, r12 = 0.f, r13 = 0.f;
                #pragma unroll
                for (int c4 = 0; c4 < 8; ++c4) {
                    float4 q0 = *((const float4*)(fbw + slot * 72 + c4 * 4));
                    float4 q1 = *((const float4*)(fbw + slot * 72 + 36 + c4 * 4));
                    const float* wp = wbw + c4 * 128 + coq * 4;
                    float4 wa = *((const float4*)(wp));
                    float4 wb = *((const float4*)(wp + 32));
                    float4 wc = *((const float4*)(wp + 64));
                    float4 wd = *((const float4*)(wp + 96));
                    r00 += q0.x * wa.x; r01 += q0.x * wa.y; r02 += q0.x * wa.z; r03 += q0.x * wa.w;
                    r00 += q0.y * wb.x; r01 += q0.y * wb.y; r02 += q0.y * wb.z; r03 += q0.y * wb.w;
                    r00 += q0.z * wc.x; r01 += q0.z * wc.y; r02 += q0.z * wc.z; r03 += q0.z * wc.w;
                    r00 += q0.w * wd.x; r01 += q0.w * wd.y; r02 += q0.w * wd.z; r03 += q0.w * wd.w;
                    r10 += q1.x * wa.x; r11 += q1.x * wa.y; r12 += q1.x * wa.z; r13 += q1.x * wa.w;
                    r10 += q1.y * wb.x; r11 += q1.y * wb.y; r12 += q1.y * wb.z; r13 += q1.y * wb.w;
                    r10 += q1.z * wc.x; r11 += q1.z * wc.y; r12 += q1.z * wc.z; r13 += q1.z * wc.w;
                    r10 += q1.w * wd.x; r11 += q1.w * wd.y; r12 += q1.w * wd.z; r13 += q1.w * wd.w;
                }
                if (e0u != INV) {
                    float4* ap = (float4*)(accw + (int)(e0u >> 24) * 36 + coq * 4);
                    float4 av = *ap;
                    av.x += r00; av.y += r01; av.z += r02; av.w += r03;
                    *ap = av;
                }
                if (e1u != INV) {
                    float4* ap = (float4*)(accw + (int)(e1u >> 24) * 36 + coq * 4);
                    float4 av = *ap;
                    av.x += r10; av.y += r11; av.z += r12; av.w += r13;
                    *ap = av;
                }
            } else {
                float r00 = 0.f, r01 = 0.f, r02 = 0.f, r03 = 0.f;
                #pragma unroll
                for (int c4 = 0; c4 < 8; ++c4) {
                    float4 q0 = *((const float4*)(fbw + slot * 72 + c4 * 4));
                    const float* wp = wbw + c4 * 128 + coq * 4;
                    float4 wa = *((const float4*)(wp));
                    float4 wb = *((const float4*)(wp + 32));
                    float4 wc = *((const float4*)(wp + 64));
                    float4 wd = *((const float4*)(wp + 96));
                    r00 += q0.x * wa.x; r01 += q0.x * wa.y; r02 += q0.x * wa.z; r03 += q0.x * wa.w;
                    r00 += q0.y * wb.x; r01 += q0.y * wb.y; r02 += q0.y * wb.z; r03 += q0.y * wb.w;
                    r00 += q0.z * wc.x; r01 += q0.z * wc.y; r02 += q0.z * wc.z; r03 += q0.z * wc.w;
                    r00 += q0.w * wd.x; r01 += q0.w * wd.y; r02 += q0.w * wd.z; r03 += q0.w * wd.w;
                }
                if (e0u != INV) {
                    float4* ap = (float4*)(accw + (int)(e0u >> 24) * 36 + coq * 4);
                    float4 av = *ap;
                    av.x += r00; av.y += r01; av.z += r02; av.w += r03;
                    *ap = av;
                }
            }
        }
        // rotate pipeline state
        L_cur = Ln1; L_nxt = Ln2;
        w0c = nw0; w1c = nw1; w2c = nw2; w3c = nw3;
        g0c = ng0; g1c = ng1;
        e0c = e0n; e1c = e1n;
        e0n = e0f; e1n = e1f;
    }
    // ---- wave-local epilogue: rows slot and slot+8 of this quarter ----
    #pragma unroll
    for (int half = 0; half < 2; ++half) {
        const int r = slot + half * 8;
        const int gi = (c << 6) + wave * 16 + r;
        if (gi < count) {
            float4 o = *((const float4*)(accw + r * 36 + coq * 4));
            float4 b = ((const float4*)bias)[coq];
            o.x += b.x; o.y += b.y; o.z += b.z; o.w += b.w;
            const int m = list[gi];
            if (ADD) {
                float4 a = ((const float4*)(addsrc + (long)m * CH))[coq];
                o.x += a.x; o.y += a.y; o.z += a.z; o.w += a.w;
            }
            if (RELU) {
                o.x = fmaxf(o.x, 0.f); o.y = fmaxf(o.y, 0.f);
                o.z = fmaxf(o.z, 0.f); o.w = fmaxf(o.w, 0.f);
            }
            ((float4*)(out + (long)m * CH))[coq] = o;
        }
    }
}

// ---------------- generative transpose conv k2 s2 ----------------

__global__ __launch_bounds__(256) void k_tconv(
    const float* __restrict__ h,
    const float* __restrict__ wt,
    const float* __restrict__ bt,
    float* __restrict__ out)
{
    __shared__ float wl[8 * 1060];
    for (int i = threadIdx.x; i < 8 * CH * CH; i += 256) {
        wl[(i >> 10) * 1060 + (i & 1023)] = wt[i];
    }
    __syncthreads();
    const int m = blockIdx.x * 256 + threadIdx.x;
    const int p = m >> 3, o = m & 7;
    float hr[CH], acc[CH];
    #pragma unroll
    for (int c4 = 0; c4 < 8; ++c4) {
        float4 v = ((const float4*)(h + (long)p * CH))[c4];
        hr[c4*4+0] = v.x; hr[c4*4+1] = v.y; hr[c4*4+2] = v.z; hr[c4*4+3] = v.w;
        float4 b = ((const float4*)bt)[c4];
        acc[c4*4+0] = b.x; acc[c4*4+1] = b.y; acc[c4*4+2] = b.z; acc[c4*4+3] = b.w;
    }
    const float* wb = wl + o * 1060;
    #pragma unroll
    for (int ci = 0; ci < CH; ++ci) {
        float hv = hr[ci];
        #pragma unroll
        for (int c4 = 0; c4 < 8; ++c4) {
            float4 w = *((const float4*)(wb + ci * CH + c4 * 4));
            acc[c4*4+0] += hv * w.x; acc[c4*4+1] += hv * w.y;
            acc[c4*4+2] += hv * w.z; acc[c4*4+3] += hv * w.w;
        }
    }
    #pragma unroll
    for (int c4 = 0; c4 < 8; ++c4) {
        ((float4*)(out + (long)m * CH))[c4] =
            make_float4(acc[c4*4+0], acc[c4*4+1], acc[c4*4+2], acc[c4*4+3]);
    }
}

// ---------------- classifier ----------------

__global__ __launch_bounds__(256) void k_classifier(
    const float* __restrict__ HS,
    const float* __restrict__ cw0, const float* __restrict__ cb0,
    const float* __restrict__ cw1, const float* __restrict__ cb1,
    const float* __restrict__ cw2, const float* __restrict__ cb2,
    float* __restrict__ outp, int so)
{
    __shared__ float w0[1024], w1[1024], w2[32], b0[32], b1[32];
    for (int i = threadIdx.x; i < 1024; i += 256) { w0[i] = cw0[i]; w1[i] = cw1[i]; }
    if (threadIdx.x < 32) {
        w2[threadIdx.x] = cw2[threadIdx.x];
        b0[threadIdx.x] = cb0[threadIdx.x];
        b1[threadIdx.x] = cb1[threadIdx.x];
    }
    __syncthreads();
    const int m = blockIdx.x * 256 + threadIdx.x;
    if (m >= M_ALL) return;
    if ((m & 7) != so) { outp[m] = 0.f; return; }
    float in[CH], h0[CH], h1[CH];
    #pragma unroll
    for (int c4 = 0; c4 < 8; ++c4) {
        float4 v = ((const float4*)(HS + (long)m * CH))[c4];
        in[c4*4+0] = v.x; in[c4*4+1] = v.y; in[c4*4+2] = v.z; in[c4*4+3] = v.w;
    }
    #pragma unroll
    for (int c = 0; c < CH; ++c) h0[c] = b0[c];
    #pragma unroll
    for (int ci = 0; ci < CH; ++ci) {
        float v = in[ci];
        #pragma unroll
        for (int c4 = 0; c4 < 8; ++c4) {
            float4 w = *((const float4*)(w0 + ci * CH + c4 * 4));
            h0[c4*4+0] += v * w.x; h0[c4*4+1] += v * w.y;
            h0[c4*4+2] += v * w.z; h0[c4*4+3] += v * w.w;
        }
    }
    #pragma unroll
    for (int c = 0; c < CH; ++c) { h0[c] = fmaxf(h0[c], 0.f); h1[c] = b1[c]; }
    #pragma unroll
    for (int ci = 0; ci < CH; ++ci) {
        float v = h0[ci];
        #pragma unroll
        for (int c4 = 0; c4 < 8; ++c4) {
            float4 w = *((const float4*)(w1 + ci * CH + c4 * 4));
            h1[c4*4+0] += v * w.x; h1[c4*4+1] += v * w.y;
            h1[c4*4+2] += v * w.z; h1[c4*4+3] += v * w.w;
        }
    }
    float o = cb2[0];
    #pragma unroll
    for (int ci = 0; ci < CH; ++ci) o += fmaxf(h1[ci], 0.f) * w2[ci];
    outp[m] = o;
}

// ---------------- host orchestration ----------------

extern "C" void kernel_launch(void* const* d_in, const int* in_sizes, int n_in,
                              void* d_out, int out_size, void* d_ws, size_t ws_size,
                              hipStream_t stream)
{
    (void)in_sizes; (void)n_in; (void)out_size; (void)ws_size;
    const float* x_low  = (const float*)d_in[0];
    const float* bi_w0  = (const float*)d_in[1];
    const float* bi_b0  = (const float*)d_in[2];
    const float* bi_w   = (const float*)d_in[3];
    const float* bi_b   = (const float*)d_in[4];
    const float* wt     = (const float*)d_in[5];
    const float* bt     = (const float*)d_in[6];
    const float* sw     = (const float*)d_in[7];
    const float* sb     = (const float*)d_in[8];
    const float* cw0    = (const float*)d_in[9];
    const float* cb0    = (const float*)d_in[10];
    const float* cw1    = (const float*)d_in[11];
    const float* cb1    = (const float*)d_in[12];
    const float* cw2    = (const float*)d_in[13];
    const float* cb2    = (const float*)d_in[14];
    const int* nbr_low  = (const int*)d_in[15];
    const int* nbr_u    = (const int*)d_in[16];
    const unsigned char* gtraw = (const unsigned char*)d_in[18];
    float* out = (float*)d_out;

    char* w = (char*)d_ws;
    size_t off = 0;
    auto carve = [&](size_t bytes) -> void* {
        void* p = w + off;
        off += (bytes + 255) & ~(size_t)255;
        return p;
    };
    float* feats = (float*)carve((size_t)M_ALL * CH * 4);
    float* A     = (float*)carve((size_t)M_ALL * CH * 4);
    float* X     = (float*)carve((size_t)M_ALL * CH * 4);
    float* HS    = (float*)carve((size_t)M_ALL * CH * 4);
    unsigned int* pent = (unsigned int*)carve((size_t)NCHMAX * NTAP * 64 * 4);
    int* pcnt4   = (int*)carve((size_t)NCHMAX * NTAP * 4 * 4);
    int* list    = (int*)carve((size_t)M_ALL * 4);
    int* list_low= (int*)carve((size_t)N_LOW * 4);
    int* bcnt    = (int*)carve(512 * 4);
    int* boff    = (int*)carve(512 * 4);
    unsigned char* valid = (unsigned char*)carve(M_ALL);
    unsigned char* gt8   = (unsigned char*)carve(M_ALL);
    int* cnt     = (int*)carve(64 * 4);

    const size_t WL = 27648;       // 27*32*32

    k_init<<<1, 64, 0, stream>>>(cnt);
    k_gt_detect<<<512, 256, 0, stream>>>(gtraw, cnt);
    k_gt_norm<<<512, 256, 0, stream>>>(gtraw, gt8, cnt);
    k_iota<<<64, 256, 0, stream>>>(list_low);

    // ---- low-resolution block (exactly 256 chunks) ----
    k_conv_low0<<<(N_LOW * CH) / 256, 256, 0, stream>>>(x_low, nbr_low, bi_w0, bi_b0, A);
    const int GL = 256;
    k_pairs3<0><<<GL, 256, 0, stream>>>(nbr_low, list_low, cnt + 8, nullptr, pcnt4, pent);
    k_convq<1,0><<<GL,256,0,stream>>>(A, X, nullptr, bi_w + 0*WL, bi_b + 0*32, list_low, cnt + 8, pcnt4, pent);
    k_convq<0,1><<<GL,256,0,stream>>>(X, A, A,       bi_w + 1*WL, bi_b + 1*32, list_low, cnt + 8, pcnt4, pent);
    k_convq<1,0><<<GL,256,0,stream>>>(A, X, nullptr, bi_w + 2*WL, bi_b + 2*32, list_low, cnt + 8, pcnt4, pent);
    k_convq<0,1><<<GL,256,0,stream>>>(X, A, A,       bi_w + 3*WL, bi_b + 3*32, list_low, cnt + 8, pcnt4, pent);
    k_convq<1,0><<<GL,256,0,stream>>>(A, X, nullptr, bi_w + 4*WL, bi_b + 4*32, list_low, cnt + 8, pcnt4, pent);
    k_convq<0,1><<<GL,256,0,stream>>>(X, A, A,       bi_w + 5*WL, bi_b + 5*32, list_low, cnt + 8, pcnt4, pent);
    k_convq<0,0><<<GL,256,0,stream>>>(A, X, nullptr, bi_w + 6*WL, bi_b + 6*32, list_low, cnt + 8, pcnt4, pent);
    k_tconv<<<512, 256, 0, stream>>>(X, wt, bt, feats);

    // ---- 8 generative stages ----
    static const int order[8] = {0, 7, 1, 6, 5, 2, 3, 4};
    for (int s = 0; s < 8; ++s) {
        const int so = order[s];
        if (s == 0) k_vcount<1><<<512,256,0,stream>>>(valid, gt8, nullptr, nullptr, nullptr, bcnt, so);
        else        k_vcount<0><<<512,256,0,stream>>>(valid, gt8, HS, feats, X, bcnt, so);
        k_scan512<<<1, 512, 0, stream>>>(bcnt, boff, cnt + s);
        k_emit<<<512, 256, 0, stream>>>(valid, boff, list);

        // stage-s valid set is a subset of the union of the first s+1 octant
        // slices -> count <= 16384*(s+1) -> chunks <= 256*(s+1)
        int GS = 256 * (s + 1);
        if (GS > NCHMAX) GS = NCHMAX;
        k_pairs3<1><<<GS, 256, 0, stream>>>(nbr_u, list, cnt + s, valid, pcnt4, pent);

        const float* sws = sw + (size_t)s * 8 * WL;
        const float* sbs = sb + (size_t)s * 8 * 32;
        const float* F0  = (s == 0) ? feats : X;
        k_convq<1,0><<<GS,256,0,stream>>>(F0, A, nullptr, sws + 0*WL, sbs + 0*32, list, cnt + s, pcnt4, pent);
        k_convq<1,0><<<GS,256,0,stream>>>(A,  X, nullptr, sws + 1*WL, sbs + 1*32, list, cnt + s, pcnt4, pent);
        k_convq<0,1><<<GS,256,0,stream>>>(X,  A, A,       sws + 2*WL, sbs + 2*32, list, cnt + s, pcnt4, pent);
        k_convq<1,0><<<GS,256,0,stream>>>(A,  X, nullptr, sws + 3*WL, sbs + 3*32, list, cnt + s, pcnt4, pent);
        k_convq<0,1><<<GS,256,0,stream>>>(X,  A, A,       sws + 4*WL, sbs + 4*32, list, cnt + s, pcnt4, pent);
        k_convq<1,0><<<GS,256,0,stream>>>(A,  X, nullptr, sws + 5*WL, sbs + 5*32, list, cnt + s, pcnt4, pent);
        k_convq<0,1><<<GS,256,0,stream>>>(X,  A, A,       sws + 6*WL, sbs + 6*32, list, cnt + s, pcnt4, pent);
        k_convq<0,0><<<GS,256,0,stream>>>(A, HS, nullptr, sws + 7*WL, sbs + 7*32, list, cnt + s, pcnt4, pent);

        k_classifier<<<512,256,0,stream>>>(HS, cw0, cb0, cw1, cb1, cw2, cb2,
                                           out + (size_t)s * M_ALL, so);
    }
}